// Round 26
// baseline (59.403 us; speedup 1.0000x reference)
//
#include <hip/hip_runtime.h>

enum { B_ = 32, T_ = 1024, V_ = 512, S_ = 128 };

static constexpr float K2   = 1.4426950408889634f;  // 1/ln2
static constexpr float LN2F = 0.6931471805599453f;
#define BOOSTI 6

typedef float f32x4 __attribute__((ext_vector_type(4)));
#define AS1 __attribute__((address_space(1)))
#define AS3 __attribute__((address_space(3)))

#define DPPI(x, ctrl) __builtin_amdgcn_update_dpp(0, (x), (ctrl), 0xF, 0xF, true)
#define DPPF(x, ctrl) __int_as_float(DPPI(__float_as_int(x), (ctrl)))
#define DPP_WSR1(x) DPPF((x), 0x138)   // lane l <- lane l-1, lane 0 <- 0

__device__ __forceinline__ float dpp_wave_max_l63(float x) {
  x = fmaxf(x, DPPF(x, 0xB1));   x = fmaxf(x, DPPF(x, 0x4E));
  x = fmaxf(x, DPPF(x, 0x124));  x = fmaxf(x, DPPF(x, 0x128));
  x = fmaxf(x, DPPF(x, 0x142));  x = fmaxf(x, DPPF(x, 0x143));
  return x;
}

// Kernel A: per (b,t) fused logsumexp + masked linear-prob table.
// Q[b][t][lane] = (pe1*v1, pe3*v3, pb*v0, pb*v2); rows t >= len[b] skipped.
__global__ __launch_bounds__(256) void ctc_pre4(
    const float* __restrict__ logits, const int* __restrict__ targets,
    const int* __restrict__ loglen, const int* __restrict__ tgtlen,
    f32x4* __restrict__ Q) {
  const int w = threadIdx.x >> 6, l = threadIdx.x & 63;
  const int row = blockIdx.x * 4 + w;          // row = b*T + t
  const int b = row >> 10;
  const int t = row & (T_ - 1);
  if (t >= loglen[b]) return;                  // dead row: never consumed
  const float* lrow = logits + (size_t)row * V_;
  const float4* r4 = (const float4*)lrow;
  float4 a = r4[l], c = r4[l + 64];
  float s = __builtin_exp2f(a.x * K2) + __builtin_exp2f(a.y * K2) +
            __builtin_exp2f(a.z * K2) + __builtin_exp2f(a.w * K2) +
            __builtin_exp2f(c.x * K2) + __builtin_exp2f(c.y * K2) +
            __builtin_exp2f(c.z * K2) + __builtin_exp2f(c.w * K2);
  #pragma unroll
  for (int off = 32; off; off >>= 1) s += __shfl_xor(s, off, 64);
  const float sh = (float)BOOSTI - __builtin_log2f(s);

  const int2 ee = ((const int2*)(targets + b * S_))[l];
  const int tl = tgtlen[b];
  const float lgb = __shfl(a.x, 0, 64);        // blank logit (elem 0)
  const float lg1 = lrow[ee.x];
  const float lg3 = lrow[ee.y];
  const float pb  = __builtin_exp2f(fmaf(lgb, K2, sh));
  const float pe1 = __builtin_exp2f(fmaf(lg1, K2, sh));
  const float pe3 = __builtin_exp2f(fmaf(lg3, K2, sh));
  const int smax = 2 * tl;
  f32x4 q;
  q.x = (4 * l + 1 <= smax) ? pe1 : 0.0f;
  q.y = (4 * l + 3 <= smax) ? pe3 : 0.0f;
  q.z = (4 * l     <= smax) ? pb  : 0.0f;
  q.w = (4 * l + 2 <= smax) ? pb  : 0.0f;
  Q[(size_t)row * 64 + l] = q;
}

// Kernel B: producer-consumer (R21-proven) with a 13-VALU COMPUTE:
//  - fmaf(n1,m1,..)/fmaf(p1,m3,..): m∈{0,1} so the product is exact and the
//    fma rounds identically to the old mul+add chain (bit-identical).
//  - v4l multiply dropped: lanes!=63 accumulate garbage p4, but A[256] is
//    only read from lane 63 (where RX.w == pb when tl==128), and renorm's
//    scale choice is power-of-2 exactly-compensated -> output bit-identical.
__global__ __launch_bounds__(128, 1) void ctc_dp7(
    const f32x4* __restrict__ Q, const int* __restrict__ targets,
    const int* __restrict__ loglen, const int* __restrict__ tgtlen,
    float* __restrict__ out) {
  __shared__ f32x4 buf[2][32 * 64];   // 2 x 32 KiB chunks
  __shared__ int flag_ready[2];
  __shared__ int flag_done[2];
  __shared__ float A[257];
  const int wv = threadIdx.x >> 6, l = threadIdx.x & 63;
  const int b = blockIdx.x;
  const int len = loglen[b], tl = tgtlen[b];
  const int nch = (len - 1 + 31) >> 5;
  const f32x4* Qb = Q + (size_t)b * T_ * 64;

  if (threadIdx.x == 0) {
    flag_ready[0] = 0; flag_ready[1] = 0;
    flag_done[0] = 0;  flag_done[1] = 0;
  }
  __syncthreads();

  if (wv == 1) {
    // ---------------- producer ----------------
    for (int c = 0; c < nch; ++c) {
      if (c >= 2) {
        while (((volatile int*)flag_done)[c & 1] < c - 1)
          __builtin_amdgcn_s_sleep(1);
      }
      const int r0 = 1 + 32 * c;
      #pragma unroll
      for (int i = 0; i < 32; ++i) {
        int row = r0 + i; if (row > T_ - 1) row = T_ - 1;
        __builtin_amdgcn_global_load_lds(
            (const AS1 void*)(const void*)(Qb + (size_t)row * 64 + l),
            (AS3 void*)(void*)(&buf[c & 1][i * 64]), 16, 0, 0);
      }
      asm volatile("s_waitcnt vmcnt(0)" ::: "memory");
      if (l == 0) ((volatile int*)flag_ready)[c & 1] = c + 1;
    }
    return;
  }

  // ---------------- consumer ----------------
  __builtin_amdgcn_s_setprio(1);

  const int2 ee = ((const int2*)(targets + b * S_))[l];
  const int e1 = ee.x, e3 = ee.y;
  const int em1 = __shfl_up(e3, 1);
  const float m1 = ((l > 0) && (e1 != 0) && (e1 != em1)) ? 1.0f : 0.0f;
  const float m3 = ((e3 != 0) && (e3 != e1)) ? 1.0f : 0.0f;

  f32x4 qi = Qb[l];                    // t = 0 init
  float p0 = (l == 0) ? qi.z : 0.0f;
  float p1 = (l == 0) ? qi.x : 0.0f;
  float p2 = 0.0f, p3 = 0.0f, p4 = 0.0f;

  const unsigned bufbase = (unsigned)(uintptr_t)(AS3 char*)(void*)&buf[0][0];

  f32x4 q0, q1, q2, q3, q4, q5, q6, q7;
#define DSRO(R, O) asm volatile("ds_read_b128 %0, %1 offset:" #O \
      : "=&v"(R) : "v"(vb))
#define WTL(R, N) asm volatile("s_waitcnt lgkmcnt(" #N ")" : "+v"(R))
#define WAIT8 asm volatile("s_waitcnt lgkmcnt(0)" \
      : "+v"(q0), "+v"(q1), "+v"(q2), "+v"(q3), \
        "+v"(q4), "+v"(q5), "+v"(q6), "+v"(q7))

#define COMPUTE(RX) { \
    const float n1_  = DPP_WSR1(p3); \
    const float w0_ = (p0 + n1_) * RX.z; \
    const float w1_ = fmaf(n1_, m1, p0 + p1) * RX.x; \
    const float w2_ = (p1 + p2) * RX.w; \
    const float w3_ = fmaf(p1, m3, p2 + p3) * RX.y; \
    const float w4_ = (p4 + p3) * RX.w; \
    p0 = w0_; p1 = w1_; p2 = w2_; p3 = w3_; p4 = w4_; \
  }

#define RENORM { \
    float m_ = fmaxf(fmaxf(fmaxf(p0, p1), fmaxf(p2, p3)), p4); \
    m_ = dpp_wave_max_l63(m_); \
    const int wm_ = __builtin_amdgcn_readlane(__float_as_int(m_), 63); \
    const int e_ = (wm_ >> 23) & 0xFF; \
    const float sc_ = __int_as_float((254 - e_) << 23); \
    p0 *= sc_; p1 *= sc_; p2 *= sc_; p3 *= sc_; p4 *= sc_; \
    shift += e_ - 127; \
  }

#define CR(R, O)  { COMPUTE(R); DSRO(R, O); }
#define TS(R, O, i)  { WTL(R, 7); if (t0 + (i) < len) COMPUTE(R); DSRO(R, O); }
#define TD(R, N, i)  { WTL(R, N); if (t0 + (i) < len) COMPUTE(R); }

  int shift = 0;
  for (int c = 0; c < nch; ++c) {
    const int t0 = 1 + 32 * c;
    while (((volatile int*)flag_ready)[c & 1] < c + 1)
      __builtin_amdgcn_s_sleep(1);
    const unsigned vb = bufbase + (unsigned)(c & 1) * 32768u + (unsigned)l * 16u;

    DSRO(q0, 0);    DSRO(q1, 1024); DSRO(q2, 2048); DSRO(q3, 3072);
    DSRO(q4, 4096); DSRO(q5, 5120); DSRO(q6, 6144); DSRO(q7, 7168);

    if (t0 + 31 < len) {
      WAIT8;   // rows 0-7 ready
      CR(q0, 8192)  CR(q1, 9216)  CR(q2, 10240) CR(q3, 11264)
      CR(q4, 12288) CR(q5, 13312) CR(q6, 14336) CR(q7, 15360)
      WAIT8;   // rows 8-15 ready
      CR(q0, 16384) CR(q1, 17408) CR(q2, 18432) CR(q3, 19456)
      CR(q4, 20480) CR(q5, 21504) CR(q6, 22528) CR(q7, 23552)
      RENORM
      WAIT8;   // rows 16-23 ready
      CR(q0, 24576) CR(q1, 25600) CR(q2, 26624) CR(q3, 27648)
      CR(q4, 28672) CR(q5, 29696) CR(q6, 30720) CR(q7, 31744)
      WAIT8;   // rows 24-31 ready
      COMPUTE(q0) COMPUTE(q1) COMPUTE(q2) COMPUTE(q3)
      COMPUTE(q4) COMPUTE(q5) COMPUTE(q6) COMPUTE(q7)
      RENORM
    } else {
      TS(q0, 8192, 0)   TS(q1, 9216, 1)   TS(q2, 10240, 2)  TS(q3, 11264, 3)
      TS(q4, 12288, 4)  TS(q5, 13312, 5)  TS(q6, 14336, 6)  TS(q7, 15360, 7)
      TS(q0, 16384, 8)  TS(q1, 17408, 9)  TS(q2, 18432, 10) TS(q3, 19456, 11)
      TS(q4, 20480, 12) TS(q5, 21504, 13) TS(q6, 22528, 14) TS(q7, 23552, 15)
      TS(q0, 24576, 16) TS(q1, 25600, 17) TS(q2, 26624, 18) TS(q3, 27648, 19)
      TS(q4, 28672, 20) TS(q5, 29696, 21) TS(q6, 30720, 22) TS(q7, 31744, 23)
      TD(q0, 7, 24) TD(q1, 6, 25) TD(q2, 5, 26) TD(q3, 4, 27)
      TD(q4, 3, 28) TD(q5, 2, 29) TD(q6, 1, 30) TD(q7, 0, 31)
    }

    asm volatile("s_waitcnt lgkmcnt(0)" ::: "memory");
    if (l == 0) ((volatile int*)flag_done)[c & 1] = c + 1;
  }

  A[4 * l + 0] = p0; A[4 * l + 1] = p1;
  A[4 * l + 2] = p2; A[4 * l + 3] = p3;
  if (l == 63) A[256] = p4;
  asm volatile("s_waitcnt lgkmcnt(0)" ::: "memory");
  if (l == 0) {
    const int ib = 2 * tl;
    const int il = (ib - 1) > 0 ? ib - 1 : 0;
    const float ab = A[ib];
    const float al = (tl > 0) ? A[il] : 0.0f;
    out[b] = -(__builtin_log2f(ab + al) + (float)(shift - BOOSTI * len)) * LN2F;
  }
}

extern "C" void kernel_launch(void* const* d_in, const int* in_sizes, int n_in,
                              void* d_out, int out_size, void* d_ws, size_t ws_size,
                              hipStream_t stream) {
  const float* logits  = (const float*)d_in[0];
  const int*   targets = (const int*)d_in[1];
  const int*   loglen  = (const int*)d_in[2];
  const int*   tgtlen  = (const int*)d_in[3];
  float* out = (float*)d_out;
  f32x4* Q = (f32x4*)d_ws;   // 32 MiB (proven sufficient R8-R25)

  ctc_pre4<<<(B_ * T_) / 4, 256, 0, stream>>>(logits, targets, loglen, tgtlen, Q);
  ctc_dp7<<<B_, 128, 0, stream>>>(Q, targets, loglen, tgtlen, out);
}